// Round 10
// baseline (620.440 us; speedup 1.0000x reference)
//
#include <hip/hip_runtime.h>

#define N_MET 100000
#define N_RXN 50000
#define E_SUB 2000000
#define E_ALL 4000000
#define MSG_DIM 16
#define HIDDEN 32

// dxdt-side binning: buckets of 256 metabolites, fixed 4096-edge tiles.
#define NBKT 391              // ceil(100000/256)
#define T_ALL 4096
#define NB_ALL 977            // ceil(4000000/4096)

// ---- Phase 1: build CSR of substrate edges by reaction (counting sort), ----
// ---- then wave-per-reaction gather-reduce. -----------------------------------
// HW model (R1-R9): scattered GLOBAL atomics are serviced memory-side at
// ~19-20 G ops/s regardless of scope/replication/footprint. LDS atomics are
// not subject to that wall — all new machinery below is LDS-atomic only.

// 1a. histogram of rxn_sub + RANK CAPTURE: the atomic's return value is this
// edge's rank within its reaction -> place needs no atomics.
__global__ __launch_bounds__(256) void hist_rank_kernel(
    const int* __restrict__ rxn_sub, int* __restrict__ count,
    int* __restrict__ rank)
{
    const int i = blockIdx.x * 256 + threadIdx.x;
    if (i >= E_SUB / 4) return;
    const int4 r = ((const int4*)rxn_sub)[i];
    int4 k;
    k.x = atomicAdd(&count[r.x], 1);
    k.y = atomicAdd(&count[r.y], 1);
    k.z = atomicAdd(&count[r.z], 1);
    k.w = atomicAdd(&count[r.w], 1);
    ((int4*)rank)[i] = k;
}

// 1b. exclusive scan of count[N_RXN] -> row_ptr[N_RXN+1]. 4 elems/thread.
__global__ __launch_bounds__(1024) void scan_kernel(
    const int* __restrict__ count, int* __restrict__ row_ptr)
{
    __shared__ int wsum[16];
    const int t = threadIdx.x;
    const int lane = t & 63;
    const int w = t >> 6;
    int carry = 0;
    for (int base = 0; base < N_RXN; base += 4096) {
        const int i0 = base + t * 4;
        const int c0 = (i0 + 0 < N_RXN) ? count[i0 + 0] : 0;
        const int c1 = (i0 + 1 < N_RXN) ? count[i0 + 1] : 0;
        const int c2 = (i0 + 2 < N_RXN) ? count[i0 + 2] : 0;
        const int c3 = (i0 + 3 < N_RXN) ? count[i0 + 3] : 0;
        const int local = c0 + c1 + c2 + c3;
        int x = local;
#pragma unroll
        for (int off = 1; off < 64; off <<= 1) {
            const int y = __shfl_up(x, off);
            if (lane >= off) x += y;
        }
        if (lane == 63) wsum[w] = x;
        __syncthreads();
        if (w == 0) {
            int s = (lane < 16) ? wsum[lane] : 0;
#pragma unroll
            for (int off = 1; off < 16; off <<= 1) {
                const int y = __shfl_up(s, off);
                if (lane >= off) s += y;
            }
            if (lane < 16) wsum[lane] = s;
        }
        __syncthreads();
        const int excl = carry + ((w > 0) ? wsum[w - 1] : 0) + x - local;
        if (i0 + 0 < N_RXN) row_ptr[i0 + 0] = excl;
        if (i0 + 1 < N_RXN) row_ptr[i0 + 1] = excl + c0;
        if (i0 + 2 < N_RXN) row_ptr[i0 + 2] = excl + c0 + c1;
        if (i0 + 3 < N_RXN) row_ptr[i0 + 3] = excl + c0 + c1 + c2;
        carry += wsum[15];
        __syncthreads();
    }
    if (t == 0) row_ptr[N_RXN] = carry;   // == E_SUB
}

// 1c. placement (ATOMIC-FREE): slot = row_ptr[r] + rank[e].
__global__ __launch_bounds__(256) void place_kernel(
    const float* __restrict__ x_met, const float* __restrict__ sto_sub,
    const int* __restrict__ met_sub, const int* __restrict__ rxn_sub,
    const int* __restrict__ rank, const int* __restrict__ row_ptr,
    float2* __restrict__ edges_sorted)
{
    const int e = blockIdx.x * 256 + threadIdx.x;
    if (e >= E_SUB) return;
    const int slot = row_ptr[rxn_sub[e]] + rank[e];
    edges_sorted[slot] = make_float2(x_met[met_sub[e]], sto_sub[e]);
}

// 1d. WAVE-PER-REACTION gather + msg-MLP + rate-MLP + softplus -> v[N_RXN].
// NOTE: j-loop is "#pragma unroll 2" — full unroll (32) hoists ~512 LDS weight
// loads, natural pressure ~256 VGPR, and any cap <=128 spills h[16] to scratch
// (rounds 5/6: 4.9/3.8 GB of HBM spill traffic). d-loops MUST stay fully
// unrolled so h[16] stays in registers.
__global__ __launch_bounds__(256, 2) void gather_rate_kernel(
    const float2* __restrict__ edges_sorted, const int* __restrict__ row_ptr,
    const float* __restrict__ W1m, const float* __restrict__ b1m,
    const float* __restrict__ W2m, const float* __restrict__ b2m,
    const float* __restrict__ W1r, const float* __restrict__ b1r,
    const float* __restrict__ W2r, const float* __restrict__ b2r,
    float* __restrict__ v)
{
    __shared__ float sW1m[2 * HIDDEN];
    __shared__ float sb1m[HIDDEN];
    __shared__ float sW2m[HIDDEN * MSG_DIM];
    __shared__ float sb2m[MSG_DIM];
    __shared__ float sW1r[MSG_DIM * HIDDEN];
    __shared__ float sb1r[HIDDEN];
    __shared__ float sW2r[HIDDEN];
    __shared__ float sb2r;
    const int t = threadIdx.x;
    if (t < 2 * HIDDEN) sW1m[t] = W1m[t];
    if (t < HIDDEN)     sb1m[t] = b1m[t];
    for (int i = t; i < HIDDEN * MSG_DIM; i += 256) sW2m[i] = W2m[i];
    if (t < MSG_DIM)    sb2m[t] = b2m[t];
    for (int i = t; i < MSG_DIM * HIDDEN; i += 256) sW1r[i] = W1r[i];
    if (t >= 64 && t < 64 + HIDDEN) { sb1r[t - 64] = b1r[t - 64]; sW2r[t - 64] = W2r[t - 64]; }
    if (t == 128) sb2r = b2r[0];
    __syncthreads();

    const int wv   = t >> 6;
    const int lane = t & 63;
    const int r    = blockIdx.x * 4 + wv;   // grid = N_RXN/4 exactly

    const int beg = row_ptr[r];
    const int end = row_ptr[r + 1];

    float h[MSG_DIM];
#pragma unroll
    for (int d = 0; d < MSG_DIM; ++d) h[d] = 0.0f;

    for (int i = beg + lane; i < end; i += 64) {
        const float2 xs = edges_sorted[i];
#pragma unroll 2
        for (int j = 0; j < HIDDEN; ++j) {
            const float hj =
                tanhf(fmaf(xs.x, sW1m[j], fmaf(xs.y, sW1m[HIDDEN + j], sb1m[j])));
#pragma unroll
            for (int d = 0; d < MSG_DIM; ++d)
                h[d] = fmaf(hj, sW2m[j * MSG_DIM + d], h[d]);
        }
    }

    // wave-reduce h[16] (butterfly; all lanes end with the segment sum)
#pragma unroll
    for (int off = 32; off >= 1; off >>= 1) {
#pragma unroll
        for (int d = 0; d < MSG_DIM; ++d)
            h[d] += __shfl_xor(h[d], off);
    }

    // fold per-edge +b2m: cnt * b2m
    const float cnt = (float)(end - beg);
#pragma unroll
    for (int d = 0; d < MSG_DIM; ++d) h[d] = fmaf(cnt, sb2m[d], h[d]);

    // rate MLP: lane j (j<32) computes hidden unit j; reduce over 32 lanes
    float part = 0.0f;
    if (lane < HIDDEN) {
        float z = sb1r[lane];
#pragma unroll
        for (int d = 0; d < MSG_DIM; ++d)
            z = fmaf(h[d], sW1r[d * HIDDEN + lane], z);
        part = tanhf(z) * sW2r[lane];
    }
#pragma unroll
    for (int off = 16; off >= 1; off >>= 1)
        part += __shfl_xor(part, off);

    if (lane == 0) {
        const float acc = part + sb2r;
        v[r] = fmaxf(acc, 0.0f) + log1pf(expf(-fabsf(acc)));
    }
}

// ---- Phase 2: dxdt via bucket binning (NO global atomics). -------------------

// 2a. per-block LDS histogram of met_all>>8 over a fixed 4096-edge tile.
__global__ __launch_bounds__(256) void hist_all_kernel(
    const int* __restrict__ met_all, int* __restrict__ hist)
{
    __shared__ int hb[NBKT];
    const int t = threadIdx.x, bk = blockIdx.x;
    for (int i = t; i < NBKT; i += 256) hb[i] = 0;
    __syncthreads();
#pragma unroll
    for (int it = 0; it < 4; ++it) {
        const int i = bk * 1024 + it * 256 + t;
        if (i < E_ALL / 4) {
            const int4 m = ((const int4*)met_all)[i];
            atomicAdd(&hb[m.x >> 8], 1);
            atomicAdd(&hb[m.y >> 8], 1);
            atomicAdd(&hb[m.z >> 8], 1);
            atomicAdd(&hb[m.w >> 8], 1);
        }
    }
    __syncthreads();
    for (int i = t; i < NBKT; i += 256) hist[bk * NBKT + i] = hb[i];
}

// 2b. per-bucket exclusive scan over blocks: hist[bk][b] -> within-bucket
// offsets (in place); tot[b] = bucket total. One block per bucket.
__global__ __launch_bounds__(256) void scan_cols_kernel(
    int* __restrict__ hist, int* __restrict__ tot)
{
    __shared__ int wsum[4];
    const int b = blockIdx.x;
    const int t = threadIdx.x, lane = t & 63, w = t >> 6;
    int carry = 0;
    for (int basei = 0; basei < NB_ALL; basei += 256) {
        const int bk = basei + t;
        const int val = (bk < NB_ALL) ? hist[bk * NBKT + b] : 0;
        int x = val;
#pragma unroll
        for (int off = 1; off < 64; off <<= 1) {
            const int y = __shfl_up(x, off);
            if (lane >= off) x += y;
        }
        if (lane == 63) wsum[w] = x;
        __syncthreads();
        if (w == 0) {
            int s = (lane < 4) ? wsum[lane] : 0;
#pragma unroll
            for (int off = 1; off < 4; off <<= 1) {
                const int y = __shfl_up(s, off);
                if (lane >= off) s += y;
            }
            if (lane < 4) wsum[lane] = s;
        }
        __syncthreads();
        const int excl = carry + ((w > 0) ? wsum[w - 1] : 0) + x - val;
        if (bk < NB_ALL) hist[bk * NBKT + b] = excl;
        carry += wsum[3];
        __syncthreads();
    }
    if (t == 0) tot[b] = carry;
}

// 2c. exclusive scan of tot[NBKT] -> base[NBKT]. Single block.
__global__ __launch_bounds__(256) void scan_base_kernel(
    const int* __restrict__ tot, int* __restrict__ base)
{
    __shared__ int wsum[4];
    const int t = threadIdx.x, lane = t & 63, w = t >> 6;
    int carry = 0;
    for (int basei = 0; basei < NBKT; basei += 256) {
        const int i = basei + t;
        const int val = (i < NBKT) ? tot[i] : 0;
        int x = val;
#pragma unroll
        for (int off = 1; off < 64; off <<= 1) {
            const int y = __shfl_up(x, off);
            if (lane >= off) x += y;
        }
        if (lane == 63) wsum[w] = x;
        __syncthreads();
        if (w == 0) {
            int s = (lane < 4) ? wsum[lane] : 0;
#pragma unroll
            for (int off = 1; off < 4; off <<= 1) {
                const int y = __shfl_up(s, off);
                if (lane >= off) s += y;
            }
            if (lane < 4) wsum[lane] = s;
        }
        __syncthreads();
        const int excl = carry + ((w > 0) ? wsum[w - 1] : 0) + x - val;
        if (i < NBKT) base[i] = excl;
        carry += wsum[3];
        __syncthreads();
    }
}

// 2d. scatter pass: replay the tile; LDS-atomic rank into per-(block,bucket)
// contiguous runs; write (contrib, met&255). Zero global atomics.
__global__ __launch_bounds__(256) void scatter_bin_kernel(
    const float* __restrict__ sto_all, const float* __restrict__ v,
    const int* __restrict__ met_all, const int* __restrict__ rxn_all,
    const int* __restrict__ hist, const int* __restrict__ base,
    float* __restrict__ pc, unsigned char* __restrict__ pm)
{
    __shared__ int offs[NBKT];
    const int t = threadIdx.x, bk = blockIdx.x;
    for (int i = t; i < NBKT; i += 256)
        offs[i] = hist[bk * NBKT + i] + base[i];
    __syncthreads();
#pragma unroll
    for (int it = 0; it < 16; ++it) {
        const int e = bk * T_ALL + it * 256 + t;
        if (e < E_ALL) {
            const int m = met_all[e];
            const float c = sto_all[e] * v[rxn_all[e]];
            const int idx = atomicAdd(&offs[m >> 8], 1);
            pc[idx] = c;
            pm[idx] = (unsigned char)(m & 255);
        }
    }
}

// 2e. one block per bucket: contiguous read of its segment, LDS accumulate
// (256 floats), coalesced dxdt write. Mets with no edges get 0.
__global__ __launch_bounds__(256) void bucket_accum_kernel(
    const float* __restrict__ pc, const unsigned char* __restrict__ pm,
    const int* __restrict__ base, const int* __restrict__ tot,
    float* __restrict__ dxdt)
{
    __shared__ float acc[256];
    const int b = blockIdx.x, t = threadIdx.x;
    acc[t] = 0.0f;
    __syncthreads();
    const int beg = base[b];
    const int end = beg + tot[b];
    for (int i = beg + t; i < end; i += 256)
        atomicAdd(&acc[pm[i]], pc[i]);
    __syncthreads();
    const int met = b * 256 + t;
    if (met < N_MET) dxdt[met] = acc[t];
}

extern "C" void kernel_launch(void* const* d_in, const int* in_sizes, int n_in,
                              void* d_out, int out_size, void* d_ws, size_t ws_size,
                              hipStream_t stream) {
    const float* x_met   = (const float*)d_in[0];
    const float* sto_sub = (const float*)d_in[1];
    const float* sto_all = (const float*)d_in[2];
    const float* W1m     = (const float*)d_in[3];
    const float* b1m     = (const float*)d_in[4];
    const float* W2m     = (const float*)d_in[5];
    const float* b2m     = (const float*)d_in[6];
    const float* W1r     = (const float*)d_in[7];
    const float* b1r     = (const float*)d_in[8];
    const float* W2r     = (const float*)d_in[9];
    const float* b2r     = (const float*)d_in[10];
    const int*   met_sub = (const int*)d_in[11];
    const int*   rxn_sub = (const int*)d_in[12];
    const int*   met_all = (const int*)d_in[13];
    const int*   rxn_all = (const int*)d_in[14];

    float* dxdt = (float*)d_out;             // [N_MET]
    float* v    = dxdt + N_MET;              // [N_RXN]

    // workspace layout (16B-aligned). pc/pm ALIAS rank/edges_sorted — their
    // lifetimes are disjoint in stream order (rank dies after place_kernel,
    // edges_sorted dies after gather_rate_kernel; pc/pm first written by
    // scatter_bin_kernel which runs after gather_rate_kernel).
    char* ws = (char*)d_ws;
    int* count   = (int*)ws;   ws += sizeof(int) * N_RXN;                       // 200000 B
    int* hist    = (int*)ws;   ws += ((sizeof(int) * NB_ALL * NBKT + 15) / 16) * 16; // ~1.53 MB
    int* tot     = (int*)ws;   ws += ((sizeof(int) * NBKT + 15) / 16) * 16;
    int* base    = (int*)ws;   ws += ((sizeof(int) * NBKT + 15) / 16) * 16;
    int* row_ptr = (int*)ws;   ws += ((sizeof(int) * (N_RXN + 1) + 15) / 16) * 16;
    char* A = ws;                                    // alias region, 24 MB
    int*    rank         = (int*)A;                  // [E_SUB]   = 8 MB
    float2* edges_sorted = (float2*)(A + (size_t)E_SUB * 4);   // [E_SUB] = 16 MB
    float*  pc           = (float*)A;                // [E_ALL]   = 16 MB (aliases rank+edges)
    unsigned char* pm    = (unsigned char*)(A + (size_t)E_ALL * 4); // [E_ALL] = 4 MB

    hipMemsetAsync(count, 0, sizeof(int) * N_RXN, stream);

    // phase 1: v
    hist_rank_kernel<<<(E_SUB / 4 + 255) / 256, 256, 0, stream>>>(
        rxn_sub, count, rank);
    scan_kernel<<<1, 1024, 0, stream>>>(count, row_ptr);
    place_kernel<<<(E_SUB + 255) / 256, 256, 0, stream>>>(
        x_met, sto_sub, met_sub, rxn_sub, rank, row_ptr, edges_sorted);
    gather_rate_kernel<<<N_RXN / 4, 256, 0, stream>>>(
        edges_sorted, row_ptr, W1m, b1m, W2m, b2m, W1r, b1r, W2r, b2r, v);

    // phase 2: dxdt (no global atomics)
    hist_all_kernel<<<NB_ALL, 256, 0, stream>>>(met_all, hist);
    scan_cols_kernel<<<NBKT, 256, 0, stream>>>(hist, tot);
    scan_base_kernel<<<1, 256, 0, stream>>>(tot, base);
    scatter_bin_kernel<<<NB_ALL, 256, 0, stream>>>(
        sto_all, v, met_all, rxn_all, hist, base, pc, pm);
    bucket_accum_kernel<<<NBKT, 256, 0, stream>>>(pc, pm, base, tot, dxdt);
}